// Round 22
// baseline (109.378 us; speedup 1.0000x reference)
//
#include <hip/hip_runtime.h>

#define NN 8
#define CC 19
#define HH 512
#define WW 512
#define HW (HH*WW)            // 262144
#define NPIX (NN*HW)          // 2097152
#define NPLANE (NN*CC)        // 152
#define BIGV (1<<20)
#define M7 0x7F7F7F7Fu

// persistent scratch in device globals (zero-initialized at module load;
// k_final restores the zero-state after each use -> replay-invariant)
__device__ unsigned char g_tT[NPIX];                  // targets transposed [n][w][h]
__device__ unsigned char g_pred[NPIX];                // row-major [n][h][w]
__device__ float g_lse[NPIX];                         // row-major
__device__ unsigned char g_inter[(size_t)NPLANE*HW];  // blocked [plane][wt:8][h:512][wl:64]
__device__ unsigned char g_pbb[(size_t)NPLANE*HW/8];  // pred-boundary bits, blocked geom
__device__ float g_ce;
__device__ float g_part[64][16];                      // padded border partials
__device__ unsigned int g_present_mask;

// bytewise x==0 -> 0x80 flag (exact, no cross-byte carry)
__device__ __forceinline__ unsigned int eqz(unsigned int x) {
  unsigned int y = (x & M7) + M7;
  return ~(y | x | M7);
}

// per-pixel softmax stats, 16 px/thread, channel-major, LOW-STATE build:
// pk[] removed (incremental CE), state m/s/a[16]=48 regs -> 3 blocks/CU
// (launch_bounds cap ~85) for 12 waves/CU of fetch concurrency.
__global__ __launch_bounds__(256, 3) void k_pixel(const float* __restrict__ slices,
                                                  const int* __restrict__ targets) {
  int bp = blockIdx.x * 4096;                   // block tile: 4096 consecutive px
  int n = bp >> 18;                             // HW = 2^18, 64 blocks/image
  int r = bp & (HW - 1);
  int wv = threadIdx.x >> 6;
  int lane = threadIdx.x & 63;
  int ob = wv * 1024 + lane * 4;                // group g offset: ob + g*256
  const float* base = slices + (size_t)n * CC * HW + r;

  // targets: 4 int4 loads -> packed bytes tw[4] (16 targets, u8 each)
  unsigned int tw[4];
#pragma unroll
  for (int g = 0; g < 4; ++g) {
    int4 t4 = ((const int4*)(targets + bp))[(ob + g * 256) >> 2];
    tw[g] = (unsigned int)(t4.x & 255) | ((unsigned int)(t4.y & 255) << 8) |
            ((unsigned int)(t4.z & 255) << 16) | ((unsigned int)(t4.w & 255) << 24);
  }

  float m[16], s[16];
  int a[16];
  float ce_pick = 0.f;
  {
#pragma unroll
    for (int g = 0; g < 4; ++g) {
      float4 x4 = *(const float4*)(base + ob + g * 256);
      float xg[4] = {x4.x, x4.y, x4.z, x4.w};
#pragma unroll
      for (int e = 0; e < 4; ++e) {
        int j = g * 4 + e;
        int tj = (int)((tw[g] >> (e * 8)) & 255u);
        m[j] = xg[e];
        a[j] = 0;
        s[j] = __expf(xg[e]);
        ce_pick += (tj == 0) ? xg[e] : 0.f;
      }
    }
  }
#pragma unroll 1
  for (int c = 1; c < CC; ++c) {
    const float* cb = base + (size_t)c * HW;
#pragma unroll
    for (int g = 0; g < 4; ++g) {
      float4 x4 = *(const float4*)(cb + ob + g * 256);
      float xg[4] = {x4.x, x4.y, x4.z, x4.w};
#pragma unroll
      for (int e = 0; e < 4; ++e) {
        int j = g * 4 + e;
        int tj = (int)((tw[g] >> (e * 8)) & 255u);
        if (xg[e] > m[j]) { m[j] = xg[e]; a[j] = c; }
        s[j] += __expf(xg[e]);
        ce_pick += (c == tj) ? xg[e] : 0.f;
      }
    }
  }

  float ce_local = 0.f;
  unsigned int msk = 0u;
#pragma unroll
  for (int g = 0; g < 4; ++g) {
    float l[4];
#pragma unroll
    for (int e = 0; e < 4; ++e) {
      int j = g * 4 + e;
      l[e] = __logf(s[j]);
      int tj = (int)((tw[g] >> (e * 8)) & 255u);
      if (tj != 255) ce_local += l[e];
      if ((unsigned)tj < CC) msk |= 1u << tj;
    }
    ((float4*)(g_lse + bp))[(ob + g * 256) >> 2] = make_float4(l[0], l[1], l[2], l[3]);
    ((uchar4*)(g_pred + bp))[(ob + g * 256) >> 2] =
        make_uchar4((unsigned char)a[g * 4], (unsigned char)a[g * 4 + 1],
                    (unsigned char)a[g * 4 + 2], (unsigned char)a[g * 4 + 3]);
    // transposed target stores [n][w][h]
#pragma unroll
    for (int e = 0; e < 4; ++e) {
      int p = bp + ob + g * 256 + e;
      int h = (p >> 9) & 511;
      int w = p & 511;
      g_tT[((size_t)n << 18) + (size_t)w * HH + h] =
          (unsigned char)((tw[g] >> (e * 8)) & 255u);
    }
  }
  ce_local -= ce_pick;   // Σ_{t≠255} lse − Σ picked (picked=0 when t==255)

  __shared__ float sred[256];
  __shared__ unsigned int smsk[256];
  sred[threadIdx.x] = ce_local;
  smsk[threadIdx.x] = msk;
  __syncthreads();
  for (int st = 128; st > 0; st >>= 1) {
    if (threadIdx.x < st) {
      sred[threadIdx.x] += sred[threadIdx.x + st];
      smsk[threadIdx.x] |= smsk[threadIdx.x + st];
    }
    __syncthreads();
  }
  if (threadIdx.x == 0) {
    atomicAdd(&g_ce, sred[0]);
    atomicOr(&g_present_mask, smsk[0]);
  }
}

// H-axis scan + merged pbb (R20-verbatim).
#define CSTRIDE 528
__global__ __launch_bounds__(512, 4) void k_hscan() {
  int plane = blockIdx.x >> 3;          // 152 planes
  int wt = blockIdx.x & 7;
  int hc = threadIdx.x >> 6;            // 8 h-chunks of 64
  int wl = threadIdx.x & 63;
  int c = plane % CC;
  int n = plane / CC;
  int w = wt * 64 + wl;

  __shared__ unsigned char s_tile[64 * CSTRIDE];   // ~33 KB

  // ---- pbb phase (independent; row-major streaming on g_pred) ----
  {
    int h2 = threadIdx.x;
    const unsigned char* row = g_pred + ((size_t)n * HH + h2) * WW + wt * 64;
    const unsigned char* rown = (h2 + 1 < HH) ? row + WW : row;   // tb pad
    uint4 c0 = *(const uint4*)(row);
    uint4 c1 = *(const uint4*)(row + 16);
    uint4 c2 = *(const uint4*)(row + 32);
    uint4 c3 = *(const uint4*)(row + 48);
    uint4 n0 = *(const uint4*)(rown);
    uint4 n1 = *(const uint4*)(rown + 16);
    uint4 n2 = *(const uint4*)(rown + 32);
    uint4 n3 = *(const uint4*)(rown + 48);
    unsigned int cwv[16] = {c0.x,c0.y,c0.z,c0.w, c1.x,c1.y,c1.z,c1.w,
                            c2.x,c2.y,c2.z,c2.w, c3.x,c3.y,c3.z,c3.w};
    unsigned int nwv[16] = {n0.x,n0.y,n0.z,n0.w, n1.x,n1.y,n1.z,n1.w,
                            n2.x,n2.y,n2.z,n2.w, n3.x,n3.y,n3.z,n3.w};
    int pl = (wt > 0) ? (int)row[-1] : (int)(cwv[0] & 255u);      // w=0 pad
    unsigned int w0 = 0u, w1 = 0u;
#pragma unroll
    for (int q = 0; q < 64; ++q) {
      int pc = (int)((cwv[q >> 2] >> ((q & 3) * 8)) & 255u);
      int pn = (int)((nwv[q >> 2] >> ((q & 3) * 8)) & 255u);
      bool ec = (pc == c);
      bool bb = (ec != (pn == c)) || (ec != (pl == c));
      if (q < 32) w0 |= (bb ? 1u : 0u) << q;
      else        w1 |= (bb ? 1u : 0u) << (q - 32);
      pl = pc;
    }
    unsigned char* dst = g_pbb + (((size_t)plane * 8 + wt) * HH + h2) * 8;
    *(uint2*)dst = make_uint2(w0, w1);
  }

  // ---- stage tile: 32KB contiguous -> LDS (padded cols) ----
  {
    const unsigned char* src =
        g_tT + ((size_t)n << 18) + (size_t)wt * 32768 + threadIdx.x * 64;
    int col = threadIdx.x >> 3;
    int off = (threadIdx.x & 7) * 64;
    uint4 a = *(const uint4*)(src);
    uint4 b = *(const uint4*)(src + 16);
    uint4 c4 = *(const uint4*)(src + 32);
    uint4 d = *(const uint4*)(src + 48);
    unsigned char* dst = s_tile + col * CSTRIDE + off;
    *(uint4*)(dst)      = a;
    *(uint4*)(dst + 16) = b;
    *(uint4*)(dst + 32) = c4;
    *(uint4*)(dst + 48) = d;
  }
  __syncthreads();

  const unsigned char* myCol = s_tile + wl * CSTRIDE + hc * 64;
  unsigned int cw[16];
#pragma unroll
  for (int i = 0; i < 4; ++i) {
    uint4 q = *(const uint4*)(myCol + i * 16);
    cw[4*i] = q.x; cw[4*i+1] = q.y; cw[4*i+2] = q.z; cw[4*i+3] = q.w;
  }
  unsigned int lw[16];
  if (wl > 0) {
    const unsigned char* lcol = s_tile + (wl - 1) * CSTRIDE + hc * 64;
#pragma unroll
    for (int i = 0; i < 4; ++i) {
      uint4 q = *(const uint4*)(lcol + i * 16);
      lw[4*i] = q.x; lw[4*i+1] = q.y; lw[4*i+2] = q.z; lw[4*i+3] = q.w;
    }
  } else if (w > 0) {
    const unsigned char* colL = g_tT + ((size_t)n << 18) + (size_t)(w - 1) * HH + hc * 64;
#pragma unroll
    for (int i = 0; i < 4; ++i) {
      uint4 q = *(const uint4*)(colL + i * 16);
      lw[4*i] = q.x; lw[4*i+1] = q.y; lw[4*i+2] = q.z; lw[4*i+3] = q.w;
    }
  } else {
#pragma unroll
    for (int i = 0; i < 16; ++i) lw[i] = cw[i];   // w=0: lr-pad -> el==ec
  }
  unsigned int tnl = (hc < 7) ? (unsigned int)myCol[64]
                              : ((cw[15] >> 24) & 255u);

  unsigned int bc = (unsigned int)c * 0x01010101u;
  int v[64];
  int prev = BIGV;
#pragma unroll
  for (int i = 0; i < 16; ++i) {
    unsigned int cwi = cw[i];
    unsigned int nxt = (i < 15) ? (cw[i + 1] & 255u) : tnl;
    unsigned int tnw = (cwi >> 8) | (nxt << 24);
    unsigned int zc = eqz(cwi ^ bc);
    unsigned int zn = eqz(tnw ^ bc);
    unsigned int zl = eqz(lw[i] ^ bc);
    unsigned int bb = (zc ^ zn) | (zc ^ zl);
#pragma unroll
    for (int k = 0; k < 4; ++k) {
      int bit = (int)((bb >> (8 * k + 7)) & 1u);
      prev = min(bit ? 0 : 255, prev + 1);
      v[4 * i + k] = prev;
    }
  }

  __shared__ int s_car[8][64];
  s_car[hc][wl] = v[63];
  __syncthreads();
  int F = BIGV;
#pragma unroll
  for (int i = 0; i < 7; ++i)
    if (i < hc) F = min(s_car[i][wl] + 1, F + 64);
#pragma unroll
  for (int k = 0; k < 64; ++k) v[k] = min(v[k], F + k);

#pragma unroll
  for (int k = 62; k >= 0; --k) v[k] = min(v[k], v[k + 1] + 1);

  __syncthreads();
  s_car[hc][wl] = v[0];
  __syncthreads();
  int B = BIGV;
#pragma unroll
  for (int j = 7; j >= 1; --j)
    if (j > hc) B = min(s_car[j][wl] + 1, B + 64);

  unsigned char* outb = g_inter + (((size_t)plane * 8 + wt) * HH + hc * 64) * 64 + wl;
#pragma unroll
  for (int k = 0; k < 64; ++k) {
    int outv = min(v[k], B + (63 - k));
    outb[(size_t)k * 64] = (unsigned char)outv;
  }
}

// W-axis scan + pbb-gated sparse accumulation (R18-VERBATIM — no tail!)
__global__ __launch_bounds__(512) void k_wscan(const float* __restrict__ slices) {
  int plane = blockIdx.x >> 6;          // 152 planes
  int hg = blockIdx.x & 63;             // 64 h-groups of 8 rows
  int wv = threadIdx.x >> 6;            // 8 waves
  int lane = threadIdx.x & 63;
  int h = hg * 8 + wv;
  int c = plane % CC;
  int n = plane / CC;

  const unsigned char* rowp =
      g_inter + (((size_t)plane * 8 + (lane >> 3)) * HH + h) * 64 + (lane & 7) * 8;
  uint2 r8 = *(const uint2*)rowp;
  unsigned int pbb = (unsigned int)
      g_pbb[(((size_t)plane * 8 + (lane >> 3)) * HH + h) * 8 + (lane & 7)];

  int d0[8];
#pragma unroll
  for (int k = 0; k < 4; ++k) {
    d0[k]     = (int)((r8.x >> (k * 8)) & 255u);
    d0[k + 4] = (int)((r8.y >> (k * 8)) & 255u);
  }
  int ls[8];
  ls[0] = d0[0];
#pragma unroll
  for (int k = 1; k < 8; ++k) ls[k] = min(d0[k], ls[k - 1] + 1);
  int u = ls[7] - 8 * lane;
#pragma unroll
  for (int o = 1; o < 64; o <<= 1) {
    int t = __shfl_up(u, o, 64);
    if (lane >= o) u = min(u, t);
  }
  int cf = __shfl_up(u, 1, 64);
  int carry = (lane == 0) ? BIGV : cf + 8 * (lane - 1);
  int f[8];
#pragma unroll
  for (int k = 0; k < 8; ++k) f[k] = min(ls[k], carry + k + 1);
  int bs[8];
  bs[7] = f[7];
#pragma unroll
  for (int k = 6; k >= 0; --k) bs[k] = min(f[k], bs[k + 1] + 1);
  int mm = bs[0] + 8 * lane;
#pragma unroll
  for (int o = 1; o < 64; o <<= 1) {
    int t = __shfl_down(mm, o, 64);
    if (lane + o < 64) mm = min(mm, t);
  }
  int mb = __shfl_down(mm, 1, 64);
  int carryb = (lane == 63) ? BIGV : mb - 8 * lane;

  float acc = 0.f;
#pragma unroll
  for (int k = 0; k < 8; ++k) {
    int D = min(bs[k], carryb - k);
    int d = D - 5;                        // BORDER_DILATE
    if (d > 0 && ((pbb >> k) & 1u)) {     // joint density ~0.03%
      int w = lane * 8 + k;
      int pix = (n * HH + h) * WW + w;
      float x = slices[((size_t)n * CC + c) * HW + (size_t)h * WW + w];
      float smv = __expf(x - g_lse[pix]);
      acc += smv * (float)d;
    }
  }

#pragma unroll
  for (int o = 32; o > 0; o >>= 1) acc += __shfl_down(acc, o, 64);
  if (lane == 0) {
    float pres = (g_present_mask >> c) & 1u ? 1.f : 0.f;
    atomicAdd(&g_part[blockIdx.x & 63][0], acc * pres);
  }
}

// final sum (one wave) + output; resets state for replay determinism
__global__ void k_final(float* __restrict__ out) {
  int t = threadIdx.x;
  float b = g_part[t][0];
#pragma unroll
  for (int o = 32; o > 0; o >>= 1) b += __shfl_down(b, o, 64);
  if (t == 0) {
    out[0] = g_ce + sqrtf(b);             // BORDER_WEIGHT=1, power=0.5
    g_ce = 0.f;
    g_present_mask = 0u;
  }
  g_part[t][0] = 0.f;
}

extern "C" void kernel_launch(void* const* d_in, const int* in_sizes, int n_in,
                              void* d_out, int out_size, void* d_ws, size_t ws_size,
                              hipStream_t stream) {
  const float* slices = (const float*)d_in[0];
  const int* targets = (const int*)d_in[1];
  float* out = (float*)d_out;
  (void)d_ws; (void)ws_size; (void)in_sizes; (void)n_in; (void)out_size;

  hipLaunchKernelGGL(k_pixel, dim3(NPIX / 4096), dim3(256), 0, stream, slices, targets);
  hipLaunchKernelGGL(k_hscan, dim3(NPLANE * 8), dim3(512), 0, stream);
  hipLaunchKernelGGL(k_wscan, dim3(NPLANE * 64), dim3(512), 0, stream, slices);
  hipLaunchKernelGGL(k_final, dim3(1), dim3(64), 0, stream, out);
}

// Round 23
// 109.265 us; speedup vs baseline: 1.0010x; 1.0010x over previous
//
#include <hip/hip_runtime.h>

#define NN 8
#define CC 19
#define HH 512
#define WW 512
#define HW (HH*WW)            // 262144
#define NPIX (NN*HW)          // 2097152
#define NPLANE (NN*CC)        // 152
#define BIGV (1<<20)
#define M7 0x7F7F7F7Fu

// persistent scratch in device globals (zero-initialized at module load;
// k_final restores the zero-state after each use -> replay-invariant)
__device__ unsigned char g_tT[NPIX];                  // targets transposed [n][w][h]
__device__ unsigned char g_pred[NPIX];                // row-major [n][h][w]
__device__ float g_lse[NPIX];                         // row-major
__device__ unsigned char g_inter[(size_t)NPLANE*HW];  // blocked [plane][wt:8][h:512][wl:64]
__device__ unsigned char g_pbb[(size_t)NPLANE*HW/8];  // pred-boundary bits, blocked geom
__device__ float g_ce;
__device__ float g_part[64][16];                      // padded border partials
__device__ unsigned int g_present_mask;

// bytewise x==0 -> 0x80 flag (exact, no cross-byte carry)
__device__ __forceinline__ unsigned int eqz(unsigned int x) {
  unsigned int y = (x & M7) + M7;
  return ~(y | x | M7);
}

// per-pixel softmax stats, 16 px/thread, channel-major (R22-verbatim)
__global__ __launch_bounds__(256, 3) void k_pixel(const float* __restrict__ slices,
                                                  const int* __restrict__ targets) {
  int bp = blockIdx.x * 4096;                   // block tile: 4096 consecutive px
  int n = bp >> 18;                             // HW = 2^18, 64 blocks/image
  int r = bp & (HW - 1);
  int wv = threadIdx.x >> 6;
  int lane = threadIdx.x & 63;
  int ob = wv * 1024 + lane * 4;                // group g offset: ob + g*256
  const float* base = slices + (size_t)n * CC * HW + r;

  // targets: 4 int4 loads -> packed bytes tw[4] (16 targets, u8 each)
  unsigned int tw[4];
#pragma unroll
  for (int g = 0; g < 4; ++g) {
    int4 t4 = ((const int4*)(targets + bp))[(ob + g * 256) >> 2];
    tw[g] = (unsigned int)(t4.x & 255) | ((unsigned int)(t4.y & 255) << 8) |
            ((unsigned int)(t4.z & 255) << 16) | ((unsigned int)(t4.w & 255) << 24);
  }

  float m[16], s[16];
  int a[16];
  float ce_pick = 0.f;
  {
#pragma unroll
    for (int g = 0; g < 4; ++g) {
      float4 x4 = *(const float4*)(base + ob + g * 256);
      float xg[4] = {x4.x, x4.y, x4.z, x4.w};
#pragma unroll
      for (int e = 0; e < 4; ++e) {
        int j = g * 4 + e;
        int tj = (int)((tw[g] >> (e * 8)) & 255u);
        m[j] = xg[e];
        a[j] = 0;
        s[j] = __expf(xg[e]);
        ce_pick += (tj == 0) ? xg[e] : 0.f;
      }
    }
  }
#pragma unroll 1
  for (int c = 1; c < CC; ++c) {
    const float* cb = base + (size_t)c * HW;
#pragma unroll
    for (int g = 0; g < 4; ++g) {
      float4 x4 = *(const float4*)(cb + ob + g * 256);
      float xg[4] = {x4.x, x4.y, x4.z, x4.w};
#pragma unroll
      for (int e = 0; e < 4; ++e) {
        int j = g * 4 + e;
        int tj = (int)((tw[g] >> (e * 8)) & 255u);
        if (xg[e] > m[j]) { m[j] = xg[e]; a[j] = c; }
        s[j] += __expf(xg[e]);
        ce_pick += (c == tj) ? xg[e] : 0.f;
      }
    }
  }

  float ce_local = 0.f;
  unsigned int msk = 0u;
#pragma unroll
  for (int g = 0; g < 4; ++g) {
    float l[4];
#pragma unroll
    for (int e = 0; e < 4; ++e) {
      int j = g * 4 + e;
      l[e] = __logf(s[j]);
      int tj = (int)((tw[g] >> (e * 8)) & 255u);
      if (tj != 255) ce_local += l[e];
      if ((unsigned)tj < CC) msk |= 1u << tj;
    }
    ((float4*)(g_lse + bp))[(ob + g * 256) >> 2] = make_float4(l[0], l[1], l[2], l[3]);
    ((uchar4*)(g_pred + bp))[(ob + g * 256) >> 2] =
        make_uchar4((unsigned char)a[g * 4], (unsigned char)a[g * 4 + 1],
                    (unsigned char)a[g * 4 + 2], (unsigned char)a[g * 4 + 3]);
    // transposed target stores [n][w][h]
#pragma unroll
    for (int e = 0; e < 4; ++e) {
      int p = bp + ob + g * 256 + e;
      int h = (p >> 9) & 511;
      int w = p & 511;
      g_tT[((size_t)n << 18) + (size_t)w * HH + h] =
          (unsigned char)((tw[g] >> (e * 8)) & 255u);
    }
  }
  ce_local -= ce_pick;   // Σ_{t≠255} lse − Σ picked (picked=0 when t==255)

  __shared__ float sred[256];
  __shared__ unsigned int smsk[256];
  sred[threadIdx.x] = ce_local;
  smsk[threadIdx.x] = msk;
  __syncthreads();
  for (int st = 128; st > 0; st >>= 1) {
    if (threadIdx.x < st) {
      sred[threadIdx.x] += sred[threadIdx.x + st];
      smsk[threadIdx.x] |= smsk[threadIdx.x + st];
    }
    __syncthreads();
  }
  if (threadIdx.x == 0) {
    atomicAdd(&g_ce, sred[0]);
    atomicOr(&g_present_mask, smsk[0]);
  }
}

// H-axis scan + merged pbb. ONLY change vs R22: launch_bounds (512,2)
// -> 256-VGPR cap so cw[16]+lw[16]+v[64] provably stay in registers
// (R15/R16/R19 showed the 128-cap allocator demotes arrays to scratch).
#define CSTRIDE 528
__global__ __launch_bounds__(512, 2) void k_hscan() {
  int plane = blockIdx.x >> 3;          // 152 planes
  int wt = blockIdx.x & 7;
  int hc = threadIdx.x >> 6;            // 8 h-chunks of 64
  int wl = threadIdx.x & 63;
  int c = plane % CC;
  int n = plane / CC;
  int w = wt * 64 + wl;

  __shared__ unsigned char s_tile[64 * CSTRIDE];   // ~33 KB

  // ---- pbb phase (independent; row-major streaming on g_pred) ----
  {
    int h2 = threadIdx.x;
    const unsigned char* row = g_pred + ((size_t)n * HH + h2) * WW + wt * 64;
    const unsigned char* rown = (h2 + 1 < HH) ? row + WW : row;   // tb pad
    uint4 c0 = *(const uint4*)(row);
    uint4 c1 = *(const uint4*)(row + 16);
    uint4 c2 = *(const uint4*)(row + 32);
    uint4 c3 = *(const uint4*)(row + 48);
    uint4 n0 = *(const uint4*)(rown);
    uint4 n1 = *(const uint4*)(rown + 16);
    uint4 n2 = *(const uint4*)(rown + 32);
    uint4 n3 = *(const uint4*)(rown + 48);
    unsigned int cwv[16] = {c0.x,c0.y,c0.z,c0.w, c1.x,c1.y,c1.z,c1.w,
                            c2.x,c2.y,c2.z,c2.w, c3.x,c3.y,c3.z,c3.w};
    unsigned int nwv[16] = {n0.x,n0.y,n0.z,n0.w, n1.x,n1.y,n1.z,n1.w,
                            n2.x,n2.y,n2.z,n2.w, n3.x,n3.y,n3.z,n3.w};
    int pl = (wt > 0) ? (int)row[-1] : (int)(cwv[0] & 255u);      // w=0 pad
    unsigned int w0 = 0u, w1 = 0u;
#pragma unroll
    for (int q = 0; q < 64; ++q) {
      int pc = (int)((cwv[q >> 2] >> ((q & 3) * 8)) & 255u);
      int pn = (int)((nwv[q >> 2] >> ((q & 3) * 8)) & 255u);
      bool ec = (pc == c);
      bool bb = (ec != (pn == c)) || (ec != (pl == c));
      if (q < 32) w0 |= (bb ? 1u : 0u) << q;
      else        w1 |= (bb ? 1u : 0u) << (q - 32);
      pl = pc;
    }
    unsigned char* dst = g_pbb + (((size_t)plane * 8 + wt) * HH + h2) * 8;
    *(uint2*)dst = make_uint2(w0, w1);
  }

  // ---- stage tile: 32KB contiguous -> LDS (padded cols) ----
  {
    const unsigned char* src =
        g_tT + ((size_t)n << 18) + (size_t)wt * 32768 + threadIdx.x * 64;
    int col = threadIdx.x >> 3;
    int off = (threadIdx.x & 7) * 64;
    uint4 a = *(const uint4*)(src);
    uint4 b = *(const uint4*)(src + 16);
    uint4 c4 = *(const uint4*)(src + 32);
    uint4 d = *(const uint4*)(src + 48);
    unsigned char* dst = s_tile + col * CSTRIDE + off;
    *(uint4*)(dst)      = a;
    *(uint4*)(dst + 16) = b;
    *(uint4*)(dst + 32) = c4;
    *(uint4*)(dst + 48) = d;
  }
  __syncthreads();

  const unsigned char* myCol = s_tile + wl * CSTRIDE + hc * 64;
  unsigned int cw[16];
#pragma unroll
  for (int i = 0; i < 4; ++i) {
    uint4 q = *(const uint4*)(myCol + i * 16);
    cw[4*i] = q.x; cw[4*i+1] = q.y; cw[4*i+2] = q.z; cw[4*i+3] = q.w;
  }
  unsigned int lw[16];
  if (wl > 0) {
    const unsigned char* lcol = s_tile + (wl - 1) * CSTRIDE + hc * 64;
#pragma unroll
    for (int i = 0; i < 4; ++i) {
      uint4 q = *(const uint4*)(lcol + i * 16);
      lw[4*i] = q.x; lw[4*i+1] = q.y; lw[4*i+2] = q.z; lw[4*i+3] = q.w;
    }
  } else if (w > 0) {
    const unsigned char* colL = g_tT + ((size_t)n << 18) + (size_t)(w - 1) * HH + hc * 64;
#pragma unroll
    for (int i = 0; i < 4; ++i) {
      uint4 q = *(const uint4*)(colL + i * 16);
      lw[4*i] = q.x; lw[4*i+1] = q.y; lw[4*i+2] = q.z; lw[4*i+3] = q.w;
    }
  } else {
#pragma unroll
    for (int i = 0; i < 16; ++i) lw[i] = cw[i];   // w=0: lr-pad -> el==ec
  }
  unsigned int tnl = (hc < 7) ? (unsigned int)myCol[64]
                              : ((cw[15] >> 24) & 255u);

  unsigned int bc = (unsigned int)c * 0x01010101u;
  int v[64];
  int prev = BIGV;
#pragma unroll
  for (int i = 0; i < 16; ++i) {
    unsigned int cwi = cw[i];
    unsigned int nxt = (i < 15) ? (cw[i + 1] & 255u) : tnl;
    unsigned int tnw = (cwi >> 8) | (nxt << 24);
    unsigned int zc = eqz(cwi ^ bc);
    unsigned int zn = eqz(tnw ^ bc);
    unsigned int zl = eqz(lw[i] ^ bc);
    unsigned int bb = (zc ^ zn) | (zc ^ zl);
#pragma unroll
    for (int k = 0; k < 4; ++k) {
      int bit = (int)((bb >> (8 * k + 7)) & 1u);
      prev = min(bit ? 0 : 255, prev + 1);
      v[4 * i + k] = prev;
    }
  }

  __shared__ int s_car[8][64];
  s_car[hc][wl] = v[63];
  __syncthreads();
  int F = BIGV;
#pragma unroll
  for (int i = 0; i < 7; ++i)
    if (i < hc) F = min(s_car[i][wl] + 1, F + 64);
#pragma unroll
  for (int k = 0; k < 64; ++k) v[k] = min(v[k], F + k);

#pragma unroll
  for (int k = 62; k >= 0; --k) v[k] = min(v[k], v[k + 1] + 1);

  __syncthreads();
  s_car[hc][wl] = v[0];
  __syncthreads();
  int B = BIGV;
#pragma unroll
  for (int j = 7; j >= 1; --j)
    if (j > hc) B = min(s_car[j][wl] + 1, B + 64);

  unsigned char* outb = g_inter + (((size_t)plane * 8 + wt) * HH + hc * 64) * 64 + wl;
#pragma unroll
  for (int k = 0; k < 64; ++k) {
    int outv = min(v[k], B + (63 - k));
    outb[(size_t)k * 64] = (unsigned char)outv;
  }
}

// W-axis scan + pbb-gated sparse accumulation (R18-VERBATIM — no tail!)
__global__ __launch_bounds__(512) void k_wscan(const float* __restrict__ slices) {
  int plane = blockIdx.x >> 6;          // 152 planes
  int hg = blockIdx.x & 63;             // 64 h-groups of 8 rows
  int wv = threadIdx.x >> 6;            // 8 waves
  int lane = threadIdx.x & 63;
  int h = hg * 8 + wv;
  int c = plane % CC;
  int n = plane / CC;

  const unsigned char* rowp =
      g_inter + (((size_t)plane * 8 + (lane >> 3)) * HH + h) * 64 + (lane & 7) * 8;
  uint2 r8 = *(const uint2*)rowp;
  unsigned int pbb = (unsigned int)
      g_pbb[(((size_t)plane * 8 + (lane >> 3)) * HH + h) * 8 + (lane & 7)];

  int d0[8];
#pragma unroll
  for (int k = 0; k < 4; ++k) {
    d0[k]     = (int)((r8.x >> (k * 8)) & 255u);
    d0[k + 4] = (int)((r8.y >> (k * 8)) & 255u);
  }
  int ls[8];
  ls[0] = d0[0];
#pragma unroll
  for (int k = 1; k < 8; ++k) ls[k] = min(d0[k], ls[k - 1] + 1);
  int u = ls[7] - 8 * lane;
#pragma unroll
  for (int o = 1; o < 64; o <<= 1) {
    int t = __shfl_up(u, o, 64);
    if (lane >= o) u = min(u, t);
  }
  int cf = __shfl_up(u, 1, 64);
  int carry = (lane == 0) ? BIGV : cf + 8 * (lane - 1);
  int f[8];
#pragma unroll
  for (int k = 0; k < 8; ++k) f[k] = min(ls[k], carry + k + 1);
  int bs[8];
  bs[7] = f[7];
#pragma unroll
  for (int k = 6; k >= 0; --k) bs[k] = min(f[k], bs[k + 1] + 1);
  int mm = bs[0] + 8 * lane;
#pragma unroll
  for (int o = 1; o < 64; o <<= 1) {
    int t = __shfl_down(mm, o, 64);
    if (lane + o < 64) mm = min(mm, t);
  }
  int mb = __shfl_down(mm, 1, 64);
  int carryb = (lane == 63) ? BIGV : mb - 8 * lane;

  float acc = 0.f;
#pragma unroll
  for (int k = 0; k < 8; ++k) {
    int D = min(bs[k], carryb - k);
    int d = D - 5;                        // BORDER_DILATE
    if (d > 0 && ((pbb >> k) & 1u)) {     // joint density ~0.03%
      int w = lane * 8 + k;
      int pix = (n * HH + h) * WW + w;
      float x = slices[((size_t)n * CC + c) * HW + (size_t)h * WW + w];
      float smv = __expf(x - g_lse[pix]);
      acc += smv * (float)d;
    }
  }

#pragma unroll
  for (int o = 32; o > 0; o >>= 1) acc += __shfl_down(acc, o, 64);
  if (lane == 0) {
    float pres = (g_present_mask >> c) & 1u ? 1.f : 0.f;
    atomicAdd(&g_part[blockIdx.x & 63][0], acc * pres);
  }
}

// final sum (one wave) + output; resets state for replay determinism
__global__ void k_final(float* __restrict__ out) {
  int t = threadIdx.x;
  float b = g_part[t][0];
#pragma unroll
  for (int o = 32; o > 0; o >>= 1) b += __shfl_down(b, o, 64);
  if (t == 0) {
    out[0] = g_ce + sqrtf(b);             // BORDER_WEIGHT=1, power=0.5
    g_ce = 0.f;
    g_present_mask = 0u;
  }
  g_part[t][0] = 0.f;
}

extern "C" void kernel_launch(void* const* d_in, const int* in_sizes, int n_in,
                              void* d_out, int out_size, void* d_ws, size_t ws_size,
                              hipStream_t stream) {
  const float* slices = (const float*)d_in[0];
  const int* targets = (const int*)d_in[1];
  float* out = (float*)d_out;
  (void)d_ws; (void)ws_size; (void)in_sizes; (void)n_in; (void)out_size;

  hipLaunchKernelGGL(k_pixel, dim3(NPIX / 4096), dim3(256), 0, stream, slices, targets);
  hipLaunchKernelGGL(k_hscan, dim3(NPLANE * 8), dim3(512), 0, stream);
  hipLaunchKernelGGL(k_wscan, dim3(NPLANE * 64), dim3(512), 0, stream, slices);
  hipLaunchKernelGGL(k_final, dim3(1), dim3(64), 0, stream, out);
}

// Round 25
// 108.836 us; speedup vs baseline: 1.0050x; 1.0039x over previous
//
#include <hip/hip_runtime.h>

#define NN 8
#define CC 19
#define HH 512
#define WW 512
#define HW (HH*WW)            // 262144
#define NPIX (NN*HW)          // 2097152
#define NPLANE (NN*CC)        // 152
#define BIGV (1<<20)
#define M7 0x7F7F7F7Fu

// persistent scratch in device globals (zero-initialized at module load;
// k_final restores the zero-state after each use -> replay-invariant)
__device__ unsigned char g_tT[NPIX];                  // targets transposed [n][w][h]
__device__ unsigned char g_pred[NPIX];                // row-major [n][h][w]
__device__ float g_lse[NPIX];                         // row-major
__device__ unsigned char g_inter[(size_t)NPLANE*HW];  // blocked [plane][wt:8][h:512][wl:64]
__device__ unsigned char g_pbb[(size_t)NPLANE*HW/8];  // pred-boundary bits, blocked geom
__device__ float g_ce;
__device__ float g_part[64][16];                      // padded border partials
__device__ unsigned int g_present_mask;

// bytewise x==0 -> 0x80 flag (exact, no cross-byte carry)
__device__ __forceinline__ unsigned int eqz(unsigned int x) {
  unsigned int y = (x & M7) + M7;
  return ~(y | x | M7);
}

// per-pixel softmax stats, 16 px/thread, channel-major (R22/R23-verbatim)
__global__ __launch_bounds__(256, 3) void k_pixel(const float* __restrict__ slices,
                                                  const int* __restrict__ targets) {
  int bp = blockIdx.x * 4096;                   // block tile: 4096 consecutive px
  int n = bp >> 18;                             // HW = 2^18, 64 blocks/image
  int r = bp & (HW - 1);
  int wv = threadIdx.x >> 6;
  int lane = threadIdx.x & 63;
  int ob = wv * 1024 + lane * 4;                // group g offset: ob + g*256
  const float* base = slices + (size_t)n * CC * HW + r;

  // targets: 4 int4 loads -> packed bytes tw[4] (16 targets, u8 each)
  unsigned int tw[4];
#pragma unroll
  for (int g = 0; g < 4; ++g) {
    int4 t4 = ((const int4*)(targets + bp))[(ob + g * 256) >> 2];
    tw[g] = (unsigned int)(t4.x & 255) | ((unsigned int)(t4.y & 255) << 8) |
            ((unsigned int)(t4.z & 255) << 16) | ((unsigned int)(t4.w & 255) << 24);
  }

  float m[16], s[16];
  int a[16];
  float ce_pick = 0.f;
  {
#pragma unroll
    for (int g = 0; g < 4; ++g) {
      float4 x4 = *(const float4*)(base + ob + g * 256);
      float xg[4] = {x4.x, x4.y, x4.z, x4.w};
#pragma unroll
      for (int e = 0; e < 4; ++e) {
        int j = g * 4 + e;
        int tj = (int)((tw[g] >> (e * 8)) & 255u);
        m[j] = xg[e];
        a[j] = 0;
        s[j] = __expf(xg[e]);
        ce_pick += (tj == 0) ? xg[e] : 0.f;
      }
    }
  }
#pragma unroll 1
  for (int c = 1; c < CC; ++c) {
    const float* cb = base + (size_t)c * HW;
#pragma unroll
    for (int g = 0; g < 4; ++g) {
      float4 x4 = *(const float4*)(cb + ob + g * 256);
      float xg[4] = {x4.x, x4.y, x4.z, x4.w};
#pragma unroll
      for (int e = 0; e < 4; ++e) {
        int j = g * 4 + e;
        int tj = (int)((tw[g] >> (e * 8)) & 255u);
        if (xg[e] > m[j]) { m[j] = xg[e]; a[j] = c; }
        s[j] += __expf(xg[e]);
        ce_pick += (c == tj) ? xg[e] : 0.f;
      }
    }
  }

  float ce_local = 0.f;
  unsigned int msk = 0u;
#pragma unroll
  for (int g = 0; g < 4; ++g) {
    float l[4];
#pragma unroll
    for (int e = 0; e < 4; ++e) {
      int j = g * 4 + e;
      l[e] = __logf(s[j]);
      int tj = (int)((tw[g] >> (e * 8)) & 255u);
      if (tj != 255) ce_local += l[e];
      if ((unsigned)tj < CC) msk |= 1u << tj;
    }
    ((float4*)(g_lse + bp))[(ob + g * 256) >> 2] = make_float4(l[0], l[1], l[2], l[3]);
    ((uchar4*)(g_pred + bp))[(ob + g * 256) >> 2] =
        make_uchar4((unsigned char)a[g * 4], (unsigned char)a[g * 4 + 1],
                    (unsigned char)a[g * 4 + 2], (unsigned char)a[g * 4 + 3]);
    // transposed target stores [n][w][h]
#pragma unroll
    for (int e = 0; e < 4; ++e) {
      int p = bp + ob + g * 256 + e;
      int h = (p >> 9) & 511;
      int w = p & 511;
      g_tT[((size_t)n << 18) + (size_t)w * HH + h] =
          (unsigned char)((tw[g] >> (e * 8)) & 255u);
    }
  }
  ce_local -= ce_pick;   // Σ_{t≠255} lse − Σ picked (picked=0 when t==255)

  __shared__ float sred[256];
  __shared__ unsigned int smsk[256];
  sred[threadIdx.x] = ce_local;
  smsk[threadIdx.x] = msk;
  __syncthreads();
  for (int st = 128; st > 0; st >>= 1) {
    if (threadIdx.x < st) {
      sred[threadIdx.x] += sred[threadIdx.x + st];
      smsk[threadIdx.x] |= smsk[threadIdx.x + st];
    }
    __syncthreads();
  }
  if (threadIdx.x == 0) {
    atomicAdd(&g_ce, sred[0]);
    atomicOr(&g_present_mask, smsk[0]);
  }
}

// H-axis scan + merged pbb (R23-verbatim).
#define CSTRIDE 528
__global__ __launch_bounds__(512, 2) void k_hscan() {
  int plane = blockIdx.x >> 3;          // 152 planes
  int wt = blockIdx.x & 7;
  int hc = threadIdx.x >> 6;            // 8 h-chunks of 64
  int wl = threadIdx.x & 63;
  int c = plane % CC;
  int n = plane / CC;
  int w = wt * 64 + wl;

  __shared__ unsigned char s_tile[64 * CSTRIDE];   // ~33 KB

  // ---- pbb phase (independent; row-major streaming on g_pred) ----
  {
    int h2 = threadIdx.x;
    const unsigned char* row = g_pred + ((size_t)n * HH + h2) * WW + wt * 64;
    const unsigned char* rown = (h2 + 1 < HH) ? row + WW : row;   // tb pad
    uint4 c0 = *(const uint4*)(row);
    uint4 c1 = *(const uint4*)(row + 16);
    uint4 c2 = *(const uint4*)(row + 32);
    uint4 c3 = *(const uint4*)(row + 48);
    uint4 n0 = *(const uint4*)(rown);
    uint4 n1 = *(const uint4*)(rown + 16);
    uint4 n2 = *(const uint4*)(rown + 32);
    uint4 n3 = *(const uint4*)(rown + 48);
    unsigned int cwv[16] = {c0.x,c0.y,c0.z,c0.w, c1.x,c1.y,c1.z,c1.w,
                            c2.x,c2.y,c2.z,c2.w, c3.x,c3.y,c3.z,c3.w};
    unsigned int nwv[16] = {n0.x,n0.y,n0.z,n0.w, n1.x,n1.y,n1.z,n1.w,
                            n2.x,n2.y,n2.z,n2.w, n3.x,n3.y,n3.z,n3.w};
    int pl = (wt > 0) ? (int)row[-1] : (int)(cwv[0] & 255u);      // w=0 pad
    unsigned int w0 = 0u, w1 = 0u;
#pragma unroll
    for (int q = 0; q < 64; ++q) {
      int pc = (int)((cwv[q >> 2] >> ((q & 3) * 8)) & 255u);
      int pn = (int)((nwv[q >> 2] >> ((q & 3) * 8)) & 255u);
      bool ec = (pc == c);
      bool bb = (ec != (pn == c)) || (ec != (pl == c));
      if (q < 32) w0 |= (bb ? 1u : 0u) << q;
      else        w1 |= (bb ? 1u : 0u) << (q - 32);
      pl = pc;
    }
    unsigned char* dst = g_pbb + (((size_t)plane * 8 + wt) * HH + h2) * 8;
    *(uint2*)dst = make_uint2(w0, w1);
  }

  // ---- stage tile: 32KB contiguous -> LDS (padded cols) ----
  {
    const unsigned char* src =
        g_tT + ((size_t)n << 18) + (size_t)wt * 32768 + threadIdx.x * 64;
    int col = threadIdx.x >> 3;
    int off = (threadIdx.x & 7) * 64;
    uint4 a = *(const uint4*)(src);
    uint4 b = *(const uint4*)(src + 16);
    uint4 c4 = *(const uint4*)(src + 32);
    uint4 d = *(const uint4*)(src + 48);
    unsigned char* dst = s_tile + col * CSTRIDE + off;
    *(uint4*)(dst)      = a;
    *(uint4*)(dst + 16) = b;
    *(uint4*)(dst + 32) = c4;
    *(uint4*)(dst + 48) = d;
  }
  __syncthreads();

  const unsigned char* myCol = s_tile + wl * CSTRIDE + hc * 64;
  unsigned int cw[16];
#pragma unroll
  for (int i = 0; i < 4; ++i) {
    uint4 q = *(const uint4*)(myCol + i * 16);
    cw[4*i] = q.x; cw[4*i+1] = q.y; cw[4*i+2] = q.z; cw[4*i+3] = q.w;
  }
  unsigned int lw[16];
  if (wl > 0) {
    const unsigned char* lcol = s_tile + (wl - 1) * CSTRIDE + hc * 64;
#pragma unroll
    for (int i = 0; i < 4; ++i) {
      uint4 q = *(const uint4*)(lcol + i * 16);
      lw[4*i] = q.x; lw[4*i+1] = q.y; lw[4*i+2] = q.z; lw[4*i+3] = q.w;
    }
  } else if (w > 0) {
    const unsigned char* colL = g_tT + ((size_t)n << 18) + (size_t)(w - 1) * HH + hc * 64;
#pragma unroll
    for (int i = 0; i < 4; ++i) {
      uint4 q = *(const uint4*)(colL + i * 16);
      lw[4*i] = q.x; lw[4*i+1] = q.y; lw[4*i+2] = q.z; lw[4*i+3] = q.w;
    }
  } else {
#pragma unroll
    for (int i = 0; i < 16; ++i) lw[i] = cw[i];   // w=0: lr-pad -> el==ec
  }
  unsigned int tnl = (hc < 7) ? (unsigned int)myCol[64]
                              : ((cw[15] >> 24) & 255u);

  unsigned int bc = (unsigned int)c * 0x01010101u;
  int v[64];
  int prev = BIGV;
#pragma unroll
  for (int i = 0; i < 16; ++i) {
    unsigned int cwi = cw[i];
    unsigned int nxt = (i < 15) ? (cw[i + 1] & 255u) : tnl;
    unsigned int tnw = (cwi >> 8) | (nxt << 24);
    unsigned int zc = eqz(cwi ^ bc);
    unsigned int zn = eqz(tnw ^ bc);
    unsigned int zl = eqz(lw[i] ^ bc);
    unsigned int bb = (zc ^ zn) | (zc ^ zl);
#pragma unroll
    for (int k = 0; k < 4; ++k) {
      int bit = (int)((bb >> (8 * k + 7)) & 1u);
      prev = min(bit ? 0 : 255, prev + 1);
      v[4 * i + k] = prev;
    }
  }

  __shared__ int s_car[8][64];
  s_car[hc][wl] = v[63];
  __syncthreads();
  int F = BIGV;
#pragma unroll
  for (int i = 0; i < 7; ++i)
    if (i < hc) F = min(s_car[i][wl] + 1, F + 64);
#pragma unroll
  for (int k = 0; k < 64; ++k) v[k] = min(v[k], F + k);

#pragma unroll
  for (int k = 62; k >= 0; --k) v[k] = min(v[k], v[k + 1] + 1);

  __syncthreads();
  s_car[hc][wl] = v[0];
  __syncthreads();
  int B = BIGV;
#pragma unroll
  for (int j = 7; j >= 1; --j)
    if (j > hc) B = min(s_car[j][wl] + 1, B + 64);

  unsigned char* outb = g_inter + (((size_t)plane * 8 + wt) * HH + hc * 64) * 64 + wl;
#pragma unroll
  for (int k = 0; k < 64; ++k) {
    int outv = min(v[k], B + (63 - k));
    outb[(size_t)k * 64] = (unsigned char)outv;
  }
}

// W-axis scan + pbb-gated sparse accumulation (R18-VERBATIM — no tail!)
__global__ __launch_bounds__(512) void k_wscan(const float* __restrict__ slices) {
  int plane = blockIdx.x >> 6;          // 152 planes
  int hg = blockIdx.x & 63;             // 64 h-groups of 8 rows
  int wv = threadIdx.x >> 6;            // 8 waves
  int lane = threadIdx.x & 63;
  int h = hg * 8 + wv;
  int c = plane % CC;
  int n = plane / CC;

  const unsigned char* rowp =
      g_inter + (((size_t)plane * 8 + (lane >> 3)) * HH + h) * 64 + (lane & 7) * 8;
  uint2 r8 = *(const uint2*)rowp;
  unsigned int pbb = (unsigned int)
      g_pbb[(((size_t)plane * 8 + (lane >> 3)) * HH + h) * 8 + (lane & 7)];

  int d0[8];
#pragma unroll
  for (int k = 0; k < 4; ++k) {
    d0[k]     = (int)((r8.x >> (k * 8)) & 255u);
    d0[k + 4] = (int)((r8.y >> (k * 8)) & 255u);
  }
  int ls[8];
  ls[0] = d0[0];
#pragma unroll
  for (int k = 1; k < 8; ++k) ls[k] = min(d0[k], ls[k - 1] + 1);
  int u = ls[7] - 8 * lane;
#pragma unroll
  for (int o = 1; o < 64; o <<= 1) {
    int t = __shfl_up(u, o, 64);
    if (lane >= o) u = min(u, t);
  }
  int cf = __shfl_up(u, 1, 64);
  int carry = (lane == 0) ? BIGV : cf + 8 * (lane - 1);
  int f[8];
#pragma unroll
  for (int k = 0; k < 8; ++k) f[k] = min(ls[k], carry + k + 1);
  int bs[8];
  bs[7] = f[7];
#pragma unroll
  for (int k = 6; k >= 0; --k) bs[k] = min(f[k], bs[k + 1] + 1);
  int mm = bs[0] + 8 * lane;
#pragma unroll
  for (int o = 1; o < 64; o <<= 1) {
    int t = __shfl_down(mm, o, 64);
    if (lane + o < 64) mm = min(mm, t);
  }
  int mb = __shfl_down(mm, 1, 64);
  int carryb = (lane == 63) ? BIGV : mb - 8 * lane;

  float acc = 0.f;
#pragma unroll
  for (int k = 0; k < 8; ++k) {
    int D = min(bs[k], carryb - k);
    int d = D - 5;                        // BORDER_DILATE
    if (d > 0 && ((pbb >> k) & 1u)) {     // joint density ~0.03%
      int w = lane * 8 + k;
      int pix = (n * HH + h) * WW + w;
      float x = slices[((size_t)n * CC + c) * HW + (size_t)h * WW + w];
      float smv = __expf(x - g_lse[pix]);
      acc += smv * (float)d;
    }
  }

#pragma unroll
  for (int o = 32; o > 0; o >>= 1) acc += __shfl_down(acc, o, 64);
  if (lane == 0) {
    float pres = (g_present_mask >> c) & 1u ? 1.f : 0.f;
    atomicAdd(&g_part[blockIdx.x & 63][0], acc * pres);
  }
}

// final sum (one wave) + output; resets state for replay determinism
__global__ void k_final(float* __restrict__ out) {
  int t = threadIdx.x;
  float b = g_part[t][0];
#pragma unroll
  for (int o = 32; o > 0; o >>= 1) b += __shfl_down(b, o, 64);
  if (t == 0) {
    out[0] = g_ce + sqrtf(b);             // BORDER_WEIGHT=1, power=0.5
    g_ce = 0.f;
    g_present_mask = 0u;
  }
  g_part[t][0] = 0.f;
}

extern "C" void kernel_launch(void* const* d_in, const int* in_sizes, int n_in,
                              void* d_out, int out_size, void* d_ws, size_t ws_size,
                              hipStream_t stream) {
  const float* slices = (const float*)d_in[0];
  const int* targets = (const int*)d_in[1];
  float* out = (float*)d_out;
  (void)d_ws; (void)ws_size; (void)in_sizes; (void)n_in; (void)out_size;

  hipLaunchKernelGGL(k_pixel, dim3(NPIX / 4096), dim3(256), 0, stream, slices, targets);
  hipLaunchKernelGGL(k_hscan, dim3(NPLANE * 8), dim3(512), 0, stream);
  hipLaunchKernelGGL(k_wscan, dim3(NPLANE * 64), dim3(512), 0, stream, slices);
  hipLaunchKernelGGL(k_final, dim3(1), dim3(64), 0, stream, out);
}